// Round 2
// baseline (389.684 us; speedup 1.0000x reference)
//
#include <hip/hip_runtime.h>

// expRNN/modReLU recurrence, B=8192, T=784, I=1, H=30, C=10.
//
// Round 2: register-resident h + DPP exchange (no LDS in the T loop).
//   - 2048 blocks x 64 threads (1 wave). lane = (bg<<4)|lid:
//       bg  = l>>4 : local batch (0..3)   -> 4 batches/wave
//       lid = l&15 : chunk index; lane owns h rows 2*lid, 2*lid+1
//   - h augmented to 32 rows/cols: col 30 = x_t (W_ih folded), col 31 = 0.
//     Chunk 15 = (h30,h31) = (x_t, 0), maintained by lane 15 from LDS-preloaded x.
//   - Exchange: 15 independent v_mov_dpp row_ror:s (VALU pipe). Direction:
//     row_ror:s => lane i receives lane (i-s)&15 (rocPRIM row_shr convention).
//     W registers are pre-rotated at load so step s uses chunk (lid-s)&15.
//   - 2048 waves = 2 waves/SIMD; zero DS ops in the loop except one
//     broadcast b32 x-prefetch -> latency-hiding restored, DS pipe ~idle.

#define T_STEPS 784
#define NBATCH  8192
#define NH      30
#define NC      10
#define BPW     4     // batches per wave/block
#define NCH     16    // chunks (16 x 2 cols = 32 augmented)

typedef float v2f __attribute__((ext_vector_type(2)));

__device__ __forceinline__ float wval(const float* __restrict__ W_hh,
                                      const float* __restrict__ W_ih,
                                      int r, int c) {
    if (r >= NH) return 0.0f;          // pad rows 30,31
    if (c < NH)  return W_hh[r * NH + c];
    if (c == NH) return W_ih[r];       // x coefficient (augmented col 30)
    return 0.0f;                        // augmented col 31
}

__global__ __launch_bounds__(64, 2)
void rnn_modrelu_dpp(const float* __restrict__ inp,    // [B, T, 1]
                     const float* __restrict__ W_ih,   // [H, 1]
                     const float* __restrict__ W_hh,   // [H, H]
                     const float* __restrict__ b_mod,  // [H]
                     const float* __restrict__ W_lin,  // [C, H]
                     const float* __restrict__ b_lin,  // [C]
                     float* __restrict__ out)          // [B, C]
{
    __shared__ __align__(16) float xl[BPW * T_STEPS];  // 12.5 KB
    __shared__ float hl[BPW * 32];

    const int l   = threadIdx.x;
    const int blk = blockIdx.x;
    const int lid = l & 15;            // chunk index
    const int bg  = l >> 4;            // local batch 0..3

    // ---- preload x: 4 batches x 784 floats = 784 float4, coalesced ----
    {
        const float4* src = (const float4*)(inp + (size_t)blk * (BPW * T_STEPS));
        float4* dst = (float4*)xl;
        #pragma unroll
        for (int k = 0; k < 13; ++k) {
            int idx = l + 64 * k;
            if (idx < (BPW * T_STEPS) / 4) dst[idx] = src[idx];
        }
    }

    // ---- W registers, pre-rotated: step s uses chunk c = (lid - s) & 15 ----
    const int r0 = 2 * lid, r1 = 2 * lid + 1;
    v2f wa[NCH], wb[NCH];
    #pragma unroll
    for (int s = 0; s < NCH; ++s) {
        const int c = (lid - s) & 15;
        wa[s][0] = wval(W_hh, W_ih, r0, 2 * c);
        wa[s][1] = wval(W_hh, W_ih, r0, 2 * c + 1);
        wb[s][0] = wval(W_hh, W_ih, r1, 2 * c);
        wb[s][1] = wval(W_hh, W_ih, r1, 2 * c + 1);
    }
    const float bm0 = (r0 < NH) ? b_mod[r0] : 0.0f;
    const float bm1 = (r1 < NH) ? b_mod[r1] : 0.0f;

    __syncthreads();

    const float* xb = &xl[bg * T_STEPS];
    float xcur = xb[0];
    float hn0 = 0.0f, hn1 = 0.0f;      // own chunk of h (rows r0, r1)

    #pragma unroll 1
    for (int t = 0; t < T_STEPS; ++t) {
        // prefetch next x early (broadcast b32; latency hidden by 16 steps)
        const int tn = (t + 1 < T_STEPS) ? (t + 1) : (T_STEPS - 1);
        const float xnext = xb[tn];

        // rotation source pair: own chunk; chunk 15 carries (x_t, 0).
        // (for lid==15, hn0/hn1 are exactly 0: W rows 30,31 == 0, b == 0)
        const float p0 = (lid == 15) ? xcur : hn0;
        const float p1 = (lid == 15) ? 0.0f : hn1;

        v2f z0e = {0.0f, 0.0f}, z0o = {0.0f, 0.0f};
        v2f z1e = {0.0f, 0.0f}, z1o = {0.0f, 0.0f};

        { // s = 0: own chunk
            v2f hv = {p0, p1};
            z0e = __builtin_elementwise_fma(wa[0], hv, z0e);
            z1e = __builtin_elementwise_fma(wb[0], hv, z1e);
        }
#define STEP(S) { \
        float q0 = __int_as_float(__builtin_amdgcn_update_dpp( \
            0, __float_as_int(p0), 0x120 + S, 0xf, 0xf, false)); \
        float q1 = __int_as_float(__builtin_amdgcn_update_dpp( \
            0, __float_as_int(p1), 0x120 + S, 0xf, 0xf, false)); \
        v2f hv = {q0, q1}; \
        if ((S) & 1) { z0o = __builtin_elementwise_fma(wa[S], hv, z0o); \
                       z1o = __builtin_elementwise_fma(wb[S], hv, z1o); } \
        else         { z0e = __builtin_elementwise_fma(wa[S], hv, z0e); \
                       z1e = __builtin_elementwise_fma(wb[S], hv, z1e); } \
}
        STEP(1)  STEP(2)  STEP(3)  STEP(4)  STEP(5)
        STEP(6)  STEP(7)  STEP(8)  STEP(9)  STEP(10)
        STEP(11) STEP(12) STEP(13) STEP(14) STEP(15)
#undef STEP

        const v2f z0v = z0e + z0o;
        const v2f z1v = z1e + z1o;
        const float zz0 = z0v[0] + z0v[1];
        const float zz1 = z1v[0] + z1v[1];

        // modReLU: sign(z)*relu(|z|+b); pad rows stay exactly 0.
        float a0 = fmaxf(fabsf(zz0) + bm0, 0.0f);
        float a1 = fmaxf(fabsf(zz1) + bm1, 0.0f);
        hn0 = copysignf(a0, zz0);
        hn1 = copysignf(a1, zz1);

        xcur = xnext;
    }

    // ---- stash h to LDS for the classifier head ----
    hl[bg * 32 + r0] = hn0;
    hl[bg * 32 + r1] = hn1;
    __syncthreads();

    // ---- classifier: 40 outputs (4 batches x 10 classes) ----
    if (l < BPW * NC) {
        const int bbo = l / NC;
        const int c   = l % NC;
        float acc = b_lin[c];
        #pragma unroll
        for (int i = 0; i < NH; ++i) {
            acc = fmaf(W_lin[c * NH + i], hl[bbo * 32 + i], acc);
        }
        out[((size_t)blk * BPW + bbo) * NC + c] = acc;
    }
}

extern "C" void kernel_launch(void* const* d_in, const int* in_sizes, int n_in,
                              void* d_out, int out_size, void* d_ws, size_t ws_size,
                              hipStream_t stream) {
    const float* inp   = (const float*)d_in[0];
    const float* W_ih  = (const float*)d_in[1];
    const float* W_hh  = (const float*)d_in[2];
    const float* b_mod = (const float*)d_in[3];
    const float* W_lin = (const float*)d_in[4];
    const float* b_lin = (const float*)d_in[5];
    float* out = (float*)d_out;

    dim3 grid(NBATCH / BPW);   // 2048 blocks
    dim3 block(64);            // one wave
    rnn_modrelu_dpp<<<grid, block, 0, stream>>>(inp, W_ih, W_hh, b_mod,
                                                W_lin, b_lin, out);
}

// Round 3
// 306.771 us; speedup vs baseline: 1.2703x; 1.2703x over previous
//
#include <hip/hip_runtime.h>

// expRNN/modReLU recurrence, B=8192, T=784, I=1, H=30, C=10.
//
// Round 3: fused FMA+rotate. The h-exchange rides as a DPP modifier on
// v_fmac_f32/v_mul_f32 (VOP2 src0) -> zero separate v_mov_dpp instrs.
//   - 2048 blocks x 1 wave; lane = (bg<<4)|lid; 16 lanes/batch,
//     lane owns h rows r0=2*lid, r1=2*lid+1. 2 waves/SIMD.
//   - step s (1..15): chunk c=(lid-s)&15 arrives via row_ror:s (direction
//     verified numerically in round 2); W pre-rotated so indices are
//     lane-uniform. Chunk 15 is dead (h30,h31 == 0 via zero W rows/bias).
//   - x_t enters as the even-acc init: z_e = W_ih[r] * x (x group-uniform,
//     one LDS broadcast read per iter). Odd accs init via v_mul_f32_dpp.
//   - DPP hazard rule (VALU write -> DPP read of same VGPR needs 2 wait
//     states; assembler/compiler do NOT cover inline asm): hn0/hn1 are
//     written only by the modReLU asm blob which ends in s_nop 1, and the
//     loop-entry init is followed by a tied s_nop 1.

#define T_STEPS 784
#define NBATCH  8192
#define NH      30
#define NC      10
#define BPW     4     // batches per wave/block
#define NCH     16    // chunks (16 x 2 rows = 32; rows 30,31 are zero pads)

// acc += dpp(src, row_ror:S) * w   (DPP applies to VOP2 src0)
#define FMAC_DPP(acc, src, w, S) \
    asm("v_fmac_f32 %0, %1, %2 row_ror:" #S " row_mask:0xf bank_mask:0xf" \
        : "+v"(acc) : "v"(src), "v"(w))
// dst = dpp(src, row_ror:S) * w
#define MUL_DPP(dst, src, w, S) \
    asm("v_mul_f32 %0, %1, %2 row_ror:" #S " row_mask:0xf bank_mask:0xf" \
        : "=v"(dst) : "v"(src), "v"(w))

__global__ __launch_bounds__(64, 2)
void rnn_modrelu_fdpp(const float* __restrict__ inp,    // [B, T, 1]
                      const float* __restrict__ W_ih,   // [H, 1]
                      const float* __restrict__ W_hh,   // [H, H]
                      const float* __restrict__ b_mod,  // [H]
                      const float* __restrict__ W_lin,  // [C, H]
                      const float* __restrict__ b_lin,  // [C]
                      float* __restrict__ out)          // [B, C]
{
    __shared__ __align__(16) float xl[BPW * T_STEPS];  // 12.5 KB
    __shared__ __align__(16) float wl[NH * NH];        // 3.6 KB
    __shared__ float hl[BPW * 32];

    const int l   = threadIdx.x;
    const int blk = blockIdx.x;
    const int lid = l & 15;            // chunk / row-group index
    const int bg  = l >> 4;            // local batch 0..3

    // ---- preload x: 4 batches x 784 floats = 784 float4, coalesced ----
    {
        const float4* src = (const float4*)(inp + (size_t)blk * (BPW * T_STEPS));
        float4* dst = (float4*)xl;
        #pragma unroll
        for (int k = 0; k < 13; ++k) {
            int idx = l + 64 * k;
            if (idx < (BPW * T_STEPS) / 4) dst[idx] = src[idx];
        }
    }
    // ---- stage W_hh to LDS (900 floats = 225 float4, coalesced) ----
    {
        const float4* src = (const float4*)W_hh;
        float4* dst = (float4*)wl;
        #pragma unroll
        for (int k = 0; k < 4; ++k) {
            int idx = l + 64 * k;
            if (idx < (NH * NH) / 4) dst[idx] = src[idx];
        }
    }
    __syncthreads();

    // ---- per-lane pre-rotated W: step s uses chunk c=(lid-s)&15 ----
    const int r0 = 2 * lid, r1 = r0 + 1;
    const bool a0 = (r0 < NH), a1 = (r1 < NH);   // lane 15 rows 30,31 = pad
    float wa0[NCH], wa1[NCH], wb0[NCH], wb1[NCH];
    #pragma unroll
    for (int s = 0; s < NCH; ++s) {
        const int c = (lid - s) & 15;            // c==15 -> dead chunk -> 0
        const int c0 = 2 * c, c1 = 2 * c + 1;
        wa0[s] = (a0 && c < 15) ? wl[r0 * NH + c0] : 0.0f;
        wa1[s] = (a0 && c < 15) ? wl[r0 * NH + c1] : 0.0f;
        wb0[s] = (a1 && c < 15) ? wl[r1 * NH + c0] : 0.0f;
        wb1[s] = (a1 && c < 15) ? wl[r1 * NH + c1] : 0.0f;
    }
    const float wih0 = a0 ? W_ih[r0] : 0.0f;
    const float wih1 = a1 ? W_ih[r1] : 0.0f;
    const float bm0  = a0 ? b_mod[r0] : 0.0f;
    const float bm1  = a1 ? b_mod[r1] : 0.0f;

    const float* xb = &xl[bg * T_STEPS];
    float xcur = xb[0];
    float hn0 = 0.0f, hn1 = 0.0f;
    // entry hazard guard: 2 wait states between the zero-init writes and
    // the first DPP read of hn0/hn1
    asm volatile("s_nop 1" : "+v"(hn0), "+v"(hn1));

    #pragma unroll 1
    for (int t = 0; t < T_STEPS; ++t) {
        int tn = t + 1; if (tn >= T_STEPS) tn = T_STEPS - 1;
        const float xnext = xb[tn];    // broadcast b32; waited next iter

        // x term doubles as even-accumulator init
        float z0e = wih0 * xcur;
        float z1e = wih1 * xcur;
        // s = 0: own chunk, no DPP
        z0e = fmaf(wa0[0], hn0, z0e);
        z1e = fmaf(wb0[0], hn0, z1e);
        z0e = fmaf(wa1[0], hn1, z0e);
        z1e = fmaf(wb1[0], hn1, z1e);

        // s = 1: odd-accumulator init via mul_dpp (no zero-init needed)
        float z0o, z1o;
        MUL_DPP (z0o, hn0, wa0[1], 1);
        MUL_DPP (z1o, hn0, wb0[1], 1);
        FMAC_DPP(z0o, hn1, wa1[1], 1);
        FMAC_DPP(z1o, hn1, wb1[1], 1);

#define STEP_E(S) \
        FMAC_DPP(z0e, hn0, wa0[S], S); FMAC_DPP(z1e, hn0, wb0[S], S); \
        FMAC_DPP(z0e, hn1, wa1[S], S); FMAC_DPP(z1e, hn1, wb1[S], S);
#define STEP_O(S) \
        FMAC_DPP(z0o, hn0, wa0[S], S); FMAC_DPP(z1o, hn0, wb0[S], S); \
        FMAC_DPP(z0o, hn1, wa1[S], S); FMAC_DPP(z1o, hn1, wb1[S], S);

        STEP_E(2)  STEP_O(3)  STEP_E(4)  STEP_O(5)
        STEP_E(6)  STEP_O(7)  STEP_E(8)  STEP_O(9)
        STEP_E(10) STEP_O(11) STEP_E(12) STEP_O(13)
        STEP_E(14) STEP_O(15)
#undef STEP_E
#undef STEP_O

        const float zz0 = z0e + z0o;
        const float zz1 = z1e + z1o;

        // modReLU: hn = copysign(max(|z|+b, 0), z). Pad rows stay exactly 0
        // (w==0, b==0 -> z==0). Ends with s_nop 1: 2 wait states before the
        // next iteration's DPP reads of hn0/hn1 (VALU->DPP hazard).
        asm volatile(
            "v_add_f32 %0, |%2|, %4\n\t"
            "v_add_f32 %1, |%3|, %5\n\t"
            "v_max_f32 %0, 0, %0\n\t"
            "v_max_f32 %1, 0, %1\n\t"
            "v_bfi_b32 %0, %6, %0, %2\n\t"
            "v_bfi_b32 %1, %6, %1, %3\n\t"
            "s_nop 1"
            : "=&v"(hn0), "=&v"(hn1)
            : "v"(zz0), "v"(zz1), "v"(bm0), "v"(bm1), "s"(0x7fffffffu));

        xcur = xnext;
    }

    // ---- stash h to LDS for the classifier head ----
    hl[bg * 32 + r0] = hn0;
    hl[bg * 32 + r1] = hn1;
    __syncthreads();

    // ---- classifier: 40 outputs (4 batches x 10 classes) ----
    if (l < BPW * NC) {
        const int bbo = l / NC;
        const int c   = l % NC;
        float acc = b_lin[c];
        #pragma unroll
        for (int i = 0; i < NH; ++i) {
            acc = fmaf(W_lin[c * NH + i], hl[bbo * 32 + i], acc);
        }
        out[((size_t)blk * BPW + bbo) * NC + c] = acc;
    }
}

extern "C" void kernel_launch(void* const* d_in, const int* in_sizes, int n_in,
                              void* d_out, int out_size, void* d_ws, size_t ws_size,
                              hipStream_t stream) {
    const float* inp   = (const float*)d_in[0];
    const float* W_ih  = (const float*)d_in[1];
    const float* W_hh  = (const float*)d_in[2];
    const float* b_mod = (const float*)d_in[3];
    const float* W_lin = (const float*)d_in[4];
    const float* b_lin = (const float*)d_in[5];
    float* out = (float*)d_out;

    dim3 grid(NBATCH / BPW);   // 2048 blocks
    dim3 block(64);            // one wave
    rnn_modrelu_fdpp<<<grid, block, 0, stream>>>(inp, W_ih, W_hh, b_mod,
                                                 W_lin, b_lin, out);
}